// Round 4
// baseline (387.684 us; speedup 1.0000x reference)
//
#include <hip/hip_runtime.h>
#include <stdint.h>

#define NPOLAR 1024
#define KT 512
#define BLOCK 256
#define ROWS 32            // rows per block (both kernels)
#define PKP 18             // packed source row pitch: 16 words + parity + zero pad
#define XLP 33             // fused-fallback encoded row pitch

__device__ __forceinline__ uint32_t fbit(float f) {
    return (__float_as_uint(f) >> 29) & 1u;   // inputs are exactly 0.0f / 1.0f
}

// ================= Kernel 1: pack + CRC + scatter + butterfly -> packed words =============
__global__ __launch_bounds__(BLOCK, 8) void polar_pack_kernel(
    const float* __restrict__ u,
    const float* __restrict__ crc_gen,
    const int* __restrict__ info_pos,
    uint32_t* __restrict__ pko)               // [rows][32] row-major packed
{
    __shared__ uint32_t pk[ROWS * PKP];   // packed info stream per row (+parity,+0)
    __shared__ uint32_t gc[11 * 16];      // packed CRC generator columns
    __shared__ uint32_t mw[32];           // info-bit mask per dest word
    __shared__ uint32_t cw[32];           // stream rank (bits before word w)

    const int t   = threadIdx.x;
    const int blk = blockIdx.x;
    const int r   = t >> 3;               // row within block (0..31)
    const int q   = t & 7;                // 8-way part within row

    if (t < 32) mw[t] = 0;
    __syncthreads();

    for (int i = t; i < 523; i += BLOCK) {
        int pos = info_pos[i];
        atomicOr(&mw[pos >> 5], 1u << (pos & 31));
    }
    if (t < 176) {
        int j = t / 16, w = t % 16;
        uint32_t g = 0;
        #pragma unroll
        for (int i = 0; i < 32; ++i)
            g |= fbit(crc_gen[(32 * w + i) * 11 + j]) << i;
        gc[j * 16 + w] = g;
    }

    // ---- Phase A: coalesced pack 32x512 floats -> pk (shfl nibble-combine) ----
    {
        const int slot = t & 7;
        const int w0   = (t >> 3) & 15;
        const int rpar = t >> 7;          // 0 or 1
        const float4* uv = reinterpret_cast<const float4*>(u) + (size_t)blk * (ROWS * KT / 4) + t;
        #pragma unroll
        for (int i = 0; i < 16; ++i) {
            float4 f = uv[(size_t)i * 256];
            uint32_t nib = fbit(f.x) | (fbit(f.y) << 1) | (fbit(f.z) << 2) | (fbit(f.w) << 3);
            uint32_t val = nib << (slot * 4);
            val |= __shfl_xor(val, 1);
            val |= __shfl_xor(val, 2);
            val |= __shfl_xor(val, 4);
            if (slot == 0) pk[(rpar + 2 * i) * PKP + w0] = val;
        }
    }
    __syncthreads();

    // ---- ranks ----
    if (t < 32) {
        uint32_t c = 0;
        for (int v = 0; v < t; ++v) c += __popc(mw[v]);
        cw[t] = c;
    }

    // ---- Phase B: CRC-11, 8-way split per row ----
    {
        uint32_t a = pk[r * PKP + 2 * q], b = pk[r * PKP + 2 * q + 1];
        uint32_t par = 0;
        #pragma unroll
        for (int j = 0; j < 11; ++j) {
            uint32_t acc = (a & gc[j * 16 + 2 * q]) ^ (b & gc[j * 16 + 2 * q + 1]);
            par |= (uint32_t)(__popc(acc) & 1) << j;
        }
        par ^= __shfl_xor(par, 1);
        par ^= __shfl_xor(par, 2);
        par ^= __shfl_xor(par, 4);
        if (q == 0) pk[r * PKP + 16] = par;
        if (q == 1) pk[r * PKP + 17] = 0;
    }
    __syncthreads();

    // ---- Phase C: scatter via mask/rank (4 dest words per thread) ----
    uint32_t xr[4];
    {
        const uint32_t* row = &pk[r * PKP];
        #pragma unroll
        for (int j = 0; j < 4; ++j) {
            int w = 4 * q + j;
            uint32_t m = mw[w];
            uint32_t c = cw[w];
            int k = c >> 5, sh = c & 31;
            uint64_t win = (((uint64_t)row[k + 1] << 32) | row[k]) >> sh;
            uint32_t x;
            if (m == 0xFFFFFFFFu) {
                x = (uint32_t)win;
            } else {
                x = 0;
                uint32_t wv = (uint32_t)win;
                while (m) {
                    int b = __builtin_ctz(m);
                    m &= m - 1;
                    x |= (wv & 1u) << b;
                    wv >>= 1;
                }
            }
            xr[j] = x;
        }
    }

    // ---- Phase D: butterfly ----
    #pragma unroll
    for (int j = 0; j < 4; ++j) {
        uint32_t v = xr[j];
        v ^= (v >> 1)  & 0x55555555u;
        v ^= (v >> 2)  & 0x33333333u;
        v ^= (v >> 4)  & 0x0F0F0F0Fu;
        v ^= (v >> 8)  & 0x00FF00FFu;
        v ^= (v >> 16) & 0x0000FFFFu;
        xr[j] = v;
    }
    xr[0] ^= xr[1]; xr[2] ^= xr[3];
    xr[0] ^= xr[2]; xr[1] ^= xr[3];
    #pragma unroll
    for (int j = 0; j < 4; ++j) {
        uint32_t p;
        p = __shfl_xor(xr[j], 1); if ((q & 1) == 0) xr[j] ^= p;
        p = __shfl_xor(xr[j], 2); if ((q & 2) == 0) xr[j] ^= p;
        p = __shfl_xor(xr[j], 4); if ((q & 4) == 0) xr[j] ^= p;
    }

    // ---- store packed: row-major word offset r*32 + 4q == 4t  -> coalesced dwordx4 ----
    reinterpret_cast<uint4*>(pko + (size_t)blk * (ROWS * 32))[t] =
        make_uint4(xr[0], xr[1], xr[2], xr[3]);
}

// ================= Kernel 2: permuted expansion to floats (pure store stream) =============
__global__ __launch_bounds__(BLOCK, 8) void polar_expand_kernel(
    const uint32_t* __restrict__ pki,
    const int* __restrict__ perm_out,
    float* __restrict__ out)
{
    __shared__ uint32_t xl[ROWS * 32];    // linear pitch 32 (read-conflict count unaffected)
    const int t   = threadIdx.x;
    const int blk = blockIdx.x;

    reinterpret_cast<uint4*>(xl)[t] =
        reinterpret_cast<const uint4*>(pki + (size_t)blk * (ROWS * 32))[t];

    const int4 pv = reinterpret_cast<const int4*>(perm_out)[t];
    const int a0 = pv.x >> 5, s0 = pv.x & 31;
    const int a1 = pv.y >> 5, s1 = pv.y & 31;
    const int a2 = pv.z >> 5, s2 = pv.z & 31;
    const int a3 = pv.w >> 5, s3 = pv.w & 31;
    __syncthreads();

    float4* outv = reinterpret_cast<float4*>(out) + (size_t)blk * (ROWS * (NPOLAR / 4)) + t;
    #pragma unroll
    for (int k = 0; k < ROWS; ++k) {
        const uint32_t* rowp = &xl[k * 32];
        float4 o;
        o.x = (float)((rowp[a0] >> s0) & 1u);
        o.y = (float)((rowp[a1] >> s1) & 1u);
        o.z = (float)((rowp[a2] >> s2) & 1u);
        o.w = (float)((rowp[a3] >> s3) & 1u);
        outv[(size_t)k * (NPOLAR / 4)] = o;
    }
}

// ================= Fallback: proven R3 fused kernel (only if ws too small) ================
__global__ __launch_bounds__(BLOCK, 8) void polar_all_kernel(
    const float* __restrict__ u,
    const float* __restrict__ crc_gen,
    const int* __restrict__ info_pos,
    const int* __restrict__ perm_out,
    float* __restrict__ out)
{
    __shared__ uint32_t pk[ROWS * PKP];
    __shared__ uint32_t xl[ROWS * 36];
    __shared__ uint32_t gc[11 * 16];
    __shared__ uint32_t mw[32];
    __shared__ uint32_t cw[32];

    const int t = threadIdx.x, blk = blockIdx.x, r = t >> 3, q = t & 7;
    if (t < 32) mw[t] = 0;
    __syncthreads();
    for (int i = t; i < 523; i += BLOCK) {
        int pos = info_pos[i];
        atomicOr(&mw[pos >> 5], 1u << (pos & 31));
    }
    if (t < 176) {
        int j = t / 16, w = t % 16;
        uint32_t g = 0;
        #pragma unroll
        for (int i = 0; i < 32; ++i) g |= fbit(crc_gen[(32 * w + i) * 11 + j]) << i;
        gc[j * 16 + w] = g;
    }
    {
        const int slot = t & 7, w0 = (t >> 3) & 15, rpar = t >> 7;
        const float4* uv = reinterpret_cast<const float4*>(u) + (size_t)blk * (ROWS * KT / 4) + t;
        #pragma unroll
        for (int i = 0; i < 16; ++i) {
            float4 f = uv[(size_t)i * 256];
            uint32_t nib = fbit(f.x) | (fbit(f.y) << 1) | (fbit(f.z) << 2) | (fbit(f.w) << 3);
            uint32_t val = nib << (slot * 4);
            val |= __shfl_xor(val, 1); val |= __shfl_xor(val, 2); val |= __shfl_xor(val, 4);
            if (slot == 0) pk[(rpar + 2 * i) * PKP + w0] = val;
        }
    }
    __syncthreads();
    if (t < 32) {
        uint32_t c = 0;
        for (int v = 0; v < t; ++v) c += __popc(mw[v]);
        cw[t] = c;
    }
    {
        uint32_t a = pk[r * PKP + 2 * q], b = pk[r * PKP + 2 * q + 1];
        uint32_t par = 0;
        #pragma unroll
        for (int j = 0; j < 11; ++j) {
            uint32_t acc = (a & gc[j * 16 + 2 * q]) ^ (b & gc[j * 16 + 2 * q + 1]);
            par |= (uint32_t)(__popc(acc) & 1) << j;
        }
        par ^= __shfl_xor(par, 1); par ^= __shfl_xor(par, 2); par ^= __shfl_xor(par, 4);
        if (q == 0) pk[r * PKP + 16] = par;
        if (q == 1) pk[r * PKP + 17] = 0;
    }
    __syncthreads();
    uint32_t xr[4];
    {
        const uint32_t* row = &pk[r * PKP];
        #pragma unroll
        for (int j = 0; j < 4; ++j) {
            int w = 4 * q + j;
            uint32_t m = mw[w], c = cw[w];
            int k = c >> 5, sh = c & 31;
            uint64_t win = (((uint64_t)row[k + 1] << 32) | row[k]) >> sh;
            uint32_t x;
            if (m == 0xFFFFFFFFu) x = (uint32_t)win;
            else {
                x = 0; uint32_t wv = (uint32_t)win;
                while (m) { int b = __builtin_ctz(m); m &= m - 1; x |= (wv & 1u) << b; wv >>= 1; }
            }
            xr[j] = x;
        }
    }
    #pragma unroll
    for (int j = 0; j < 4; ++j) {
        uint32_t v = xr[j];
        v ^= (v >> 1) & 0x55555555u; v ^= (v >> 2) & 0x33333333u;
        v ^= (v >> 4) & 0x0F0F0F0Fu; v ^= (v >> 8) & 0x00FF00FFu;
        v ^= (v >> 16) & 0x0000FFFFu;
        xr[j] = v;
    }
    xr[0] ^= xr[1]; xr[2] ^= xr[3]; xr[0] ^= xr[2]; xr[1] ^= xr[3];
    #pragma unroll
    for (int j = 0; j < 4; ++j) {
        uint32_t p;
        p = __shfl_xor(xr[j], 1); if ((q & 1) == 0) xr[j] ^= p;
        p = __shfl_xor(xr[j], 2); if ((q & 2) == 0) xr[j] ^= p;
        p = __shfl_xor(xr[j], 4); if ((q & 4) == 0) xr[j] ^= p;
    }
    *reinterpret_cast<uint4*>(&xl[r * 36 + 4 * q]) = make_uint4(xr[0], xr[1], xr[2], xr[3]);
    __syncthreads();
    const int4 pv = reinterpret_cast<const int4*>(perm_out)[t];
    const int a0 = pv.x >> 5, s0 = pv.x & 31;
    const int a1 = pv.y >> 5, s1 = pv.y & 31;
    const int a2 = pv.z >> 5, s2 = pv.z & 31;
    const int a3 = pv.w >> 5, s3 = pv.w & 31;
    float4* outv = reinterpret_cast<float4*>(out) + (size_t)blk * (ROWS * (NPOLAR / 4)) + t;
    #pragma unroll
    for (int k = 0; k < ROWS; ++k) {
        const uint32_t* rowp = &xl[k * 36];
        float4 o;
        o.x = (float)((rowp[a0] >> s0) & 1u);
        o.y = (float)((rowp[a1] >> s1) & 1u);
        o.z = (float)((rowp[a2] >> s2) & 1u);
        o.w = (float)((rowp[a3] >> s3) & 1u);
        outv[(size_t)k * (NPOLAR / 4)] = o;
    }
}

extern "C" void kernel_launch(void* const* d_in, const int* in_sizes, int n_in,
                              void* d_out, int out_size, void* d_ws, size_t ws_size,
                              hipStream_t stream) {
    const float* u        = (const float*)d_in[0];
    const float* crc_gen  = (const float*)d_in[1];
    const int*   info_pos = (const int*)d_in[2];
    // d_in[3] = ind_gather (butterfly structure derived analytically; unused)
    const int*   perm_out = (const int*)d_in[4];
    float* out = (float*)d_out;

    const int rows = in_sizes[0] / KT;                         // 65536
    const size_t need = (size_t)rows * 32 * sizeof(uint32_t);  // 8 MB packed

    if (ws_size >= need) {
        uint32_t* pk = (uint32_t*)d_ws;
        polar_pack_kernel<<<rows / ROWS, BLOCK, 0, stream>>>(u, crc_gen, info_pos, pk);
        polar_expand_kernel<<<rows / ROWS, BLOCK, 0, stream>>>(pk, perm_out, out);
    } else {
        polar_all_kernel<<<rows / ROWS, BLOCK, 0, stream>>>(u, crc_gen, info_pos, perm_out, out);
    }
}